// Round 11
// baseline (545.337 us; speedup 1.0000x reference)
//
#include <hip/hip_runtime.h>
#include <hip/hip_bf16.h>
#include <math.h>

#define BATCH 2
#define SEQLEN 1024
#define DMODEL 1024
#define DINNER 2048
#define DSTATE 16
#define DTRANK 64
#define XDIM 96
#define KCONV 4
#define NBLOCKS 4
#define MROWS (BATCH*SEQLEN)   // 2048

#define NCHUNK 32
#define CLEN (SEQLEN/NCHUNK)   // 32
#define SUN 4

typedef short bf16x8 __attribute__((ext_vector_type(8)));
typedef unsigned short u16x8 __attribute__((ext_vector_type(8)));
typedef float f32x4 __attribute__((ext_vector_type(4)));

__device__ __forceinline__ unsigned short f2bf(float x) {
    union { float f; unsigned u; } c; c.f = x;
    unsigned r = c.u + 0x7FFFu + ((c.u >> 16) & 1u);   // RNE
    return (unsigned short)(r >> 16);
}
__device__ __forceinline__ float bf2f(unsigned short h) {
    union { unsigned u; float f; } c; c.u = (unsigned)h << 16;
    return c.f;
}

__device__ __forceinline__ void gload16(const void* src, void* dst) {
    __builtin_amdgcn_global_load_lds(
        (const __attribute__((address_space(1))) void*)src,
        (__attribute__((address_space(3))) void*)dst, 16, 0, 0);
}

// ---------------- LayerNorm + x copy (entry) -------------------------------
__global__ __launch_bounds__(256) void lnc_k(const float* __restrict__ x,
    const float* __restrict__ w, const float* __restrict__ b,
    float* __restrict__ resid, unsigned short* __restrict__ out)
{
    int row = blockIdx.x;
    int tid = threadIdx.x;
    size_t off = (size_t)row * DMODEL + tid * 4;
    float4 v = *(const float4*)(x + off);
    *(float4*)(resid + off) = v;
    float s  = v.x + v.y + v.z + v.w;
    float sq = v.x*v.x + v.y*v.y + v.z*v.z + v.w*v.w;
    #pragma unroll
    for (int o = 32; o > 0; o >>= 1) {
        s  += __shfl_down(s, o);
        sq += __shfl_down(sq, o);
    }
    __shared__ float ss[4], sq4[4];
    int wid = tid >> 6;
    if ((tid & 63) == 0) { ss[wid] = s; sq4[wid] = sq; }
    __syncthreads();
    if (tid == 0) {
        ss[0]  = ss[0] + ss[1] + ss[2] + ss[3];
        sq4[0] = sq4[0] + sq4[1] + sq4[2] + sq4[3];
    }
    __syncthreads();
    float mean = ss[0] * (1.0f / DMODEL);
    float var  = sq4[0] * (1.0f / DMODEL) - mean * mean;
    float rstd = rsqrtf(var + 1e-5f);
    float4 wv = *(const float4*)(w + tid * 4);
    float4 bv = *(const float4*)(b + tid * 4);
    ushort4 h;
    h.x = f2bf((v.x - mean) * rstd * wv.x + bv.x);
    h.y = f2bf((v.y - mean) * rstd * wv.y + bv.y);
    h.z = f2bf((v.z - mean) * rstd * wv.z + bv.z);
    h.w = f2bf((v.w - mean) * rstd * wv.w + bv.w);
    *(ushort4*)(out + off) = h;
}

// ---- fused: split-K reduce + residual add + LayerNorm ---------------------
template<int FINAL>
__global__ __launch_bounds__(256) void predln_k(
    const float* __restrict__ pout, float* __restrict__ resid,
    const float* __restrict__ w, const float* __restrict__ b,
    unsigned short* __restrict__ hb16, float* __restrict__ fout)
{
    int row = blockIdx.x;
    int tid = threadIdx.x;
    const size_t MN = (size_t)MROWS * DMODEL;
    size_t off = (size_t)row * DMODEL + tid * 4;
    float4 p0 = *(const float4*)(pout + off);
    float4 p1 = *(const float4*)(pout + off + MN);
    float4 p2 = *(const float4*)(pout + off + 2 * MN);
    float4 p3 = *(const float4*)(pout + off + 3 * MN);
    float4 r  = *(const float4*)(resid + off);
    float4 v;
    v.x = r.x + (p0.x + p1.x) + (p2.x + p3.x);
    v.y = r.y + (p0.y + p1.y) + (p2.y + p3.y);
    v.z = r.z + (p0.z + p1.z) + (p2.z + p3.z);
    v.w = r.w + (p0.w + p1.w) + (p2.w + p3.w);
    if (!FINAL) *(float4*)(resid + off) = v;

    float s  = v.x + v.y + v.z + v.w;
    float sq = v.x*v.x + v.y*v.y + v.z*v.z + v.w*v.w;
    #pragma unroll
    for (int o = 32; o > 0; o >>= 1) {
        s  += __shfl_down(s, o);
        sq += __shfl_down(sq, o);
    }
    __shared__ float ss[4], sq4[4];
    int wid = tid >> 6;
    if ((tid & 63) == 0) { ss[wid] = s; sq4[wid] = sq; }
    __syncthreads();
    if (tid == 0) {
        ss[0]  = ss[0] + ss[1] + ss[2] + ss[3];
        sq4[0] = sq4[0] + sq4[1] + sq4[2] + sq4[3];
    }
    __syncthreads();
    float mean = ss[0] * (1.0f / DMODEL);
    float var  = sq4[0] * (1.0f / DMODEL) - mean * mean;
    float rstd = rsqrtf(var + 1e-5f);
    float4 wv = *(const float4*)(w + tid * 4);
    float4 bv = *(const float4*)(b + tid * 4);
    float o0 = (v.x - mean) * rstd * wv.x + bv.x;
    float o1 = (v.y - mean) * rstd * wv.y + bv.y;
    float o2 = (v.z - mean) * rstd * wv.z + bv.z;
    float o3 = (v.w - mean) * rstd * wv.w + bv.w;
    if (FINAL) {
        *(float4*)(fout + off) = make_float4(o0, o1, o2, o3);
    } else {
        ushort4 h;
        h.x = f2bf(o0); h.y = f2bf(o1); h.z = f2bf(o2); h.w = f2bf(o3);
        *(ushort4*)(hb16 + off) = h;
    }
}

// ------ guarded weight transpose+convert: W[K][N] fp32 -> WT[N][K] bf16 ----
__global__ __launch_bounds__(256) void wtr2_k(
    const float* __restrict__ W, unsigned short* __restrict__ WT,
    int N, int K, long long wstride, long long wtstride)
{
    const float* Wl = W + (size_t)blockIdx.z * wstride;
    unsigned short* WTl = WT + (size_t)blockIdx.z * wtstride;
    __shared__ float T[64][65];
    int n0 = blockIdx.x * 64, k0 = blockIdx.y * 64;
    int tid = threadIdx.x;
    int kk = tid >> 4, nn = (tid & 15) * 4;
    #pragma unroll
    for (int p = 0; p < 4; ++p) {
        float4 v = make_float4(0.f, 0.f, 0.f, 0.f);
        if (n0 + nn + 4 <= N)
            v = *(const float4*)(Wl + (size_t)(k0 + p * 16 + kk) * N + n0 + nn);
        T[p * 16 + kk][nn + 0] = v.x;
        T[p * 16 + kk][nn + 1] = v.y;
        T[p * 16 + kk][nn + 2] = v.z;
        T[p * 16 + kk][nn + 3] = v.w;
    }
    __syncthreads();
    int n2 = tid >> 4, k2 = (tid & 15) * 4;
    #pragma unroll
    for (int p = 0; p < 4; ++p) {
        int nrow = n0 + p * 16 + n2;
        ushort4 h = {0, 0, 0, 0};
        if (nrow < N) {
            h.x = f2bf(T[k2 + 0][p * 16 + n2]);
            h.y = f2bf(T[k2 + 1][p * 16 + n2]);
            h.z = f2bf(T[k2 + 2][p * 16 + n2]);
            h.w = f2bf(T[k2 + 3][p * 16 + n2]);
        }
        *(ushort4*)(WTl + (size_t)nrow * K + k0 + k2) = h;
    }
}

// ---------------- bf16 MFMA GEMM v6: 3-buffer counted-vmcnt pipeline -------
// R6-best config (16x16x32, BN=128 large GEMMs). Neutral/negative levers
// tried: XCD swizzle (R6, kept), 4-buf one-barrier (R7), 256x128 tile
// (R8, -23us), 32x32x16 MFMA (R9, -5us). Staging-latency-bound at these
// short-K shapes; this schedule family's ceiling.
// R11: xproj moved to BN=64 grid(2,16,16)=1024 blocks (was BN=128, 256
// blocks = 1 block/CU): 4 blocks/CU cover each other's T=4-pipeline stalls.
template<int EPI, int BN, int SWZX = 0, int SWZY = 0>
__global__ __launch_bounds__(256) void mgemm6_k(
    const unsigned short* __restrict__ A,
    const unsigned short* __restrict__ BT,
    float* __restrict__ out0, float* __restrict__ out1,
    const float* __restrict__ bias,
    int N, int Kf, int Kloc)
{
    constexpr int WN = BN / 2;
    constexpr int NJ = WN / 16;
    __shared__ unsigned short As[3][128 * 32];
    __shared__ unsigned short Bs[3][BN * 32];
    int tid = threadIdx.x;
    int lane = tid & 63, w = tid >> 6;
    int wr = w >> 1, wc = w & 1;
    int bxx = blockIdx.x, byy = blockIdx.y;
    if constexpr (SWZX > 0) {
        constexpr int TOT = SWZX * SWZY;
        int f = bxx + SWZX * byy;
        int nf = (f & 7) * (TOT / 8) + (f >> 3);
        bxx = nf % SWZX; byy = nf / SWZX;
    }
    int m0 = byy * 128, n0 = bxx * BN;
    int lr = lane & 15, G = lane >> 4;

    int ra0 = w * 32 + (lane >> 2);
    int ra1 = ra0 + 16;
    int ga0 = (lane & 3) ^ ((ra0 >> 1) & 3);
    int ga1 = (lane & 3) ^ ((ra1 >> 1) & 3);
    int rb0 = w * (BN / 4) + (lane >> 2);
    int gb0 = (lane & 3) ^ ((rb0 >> 1) & 3);
    int rb1 = rb0 + 16;
    int gb1 = (lane & 3) ^ ((rb1 >> 1) & 3);

    int kz = blockIdx.z * Kloc;
    const unsigned short* pa0 = A  + (size_t)(m0 + ra0) * Kf + kz + ga0 * 8;
    const unsigned short* pa1 = A  + (size_t)(m0 + ra1) * Kf + kz + ga1 * 8;
    const unsigned short* pb0 = BT + (size_t)(n0 + rb0) * Kf + kz + gb0 * 8;
    const unsigned short* pb1 = BT + (size_t)(n0 + rb1) * Kf + kz + gb1 * 8;
    int dA0 = (w * 32) * 32, dA1 = dA0 + 16 * 32;
    int dB0 = (w * (BN / 4)) * 32, dB1 = dB0 + 16 * 32;

#define ISSUE(tt, bufi) do {                                   \
        gload16(pa0 + (tt) * 32, &As[bufi][dA0]);              \
        gload16(pa1 + (tt) * 32, &As[bufi][dA1]);              \
        gload16(pb0 + (tt) * 32, &Bs[bufi][dB0]);              \
        if (BN == 128) gload16(pb1 + (tt) * 32, &Bs[bufi][dB1]); \
    } while (0)

    f32x4 acc[4][NJ] = {};
    int T = Kloc / 32;

    ISSUE(0, 0);
    if (T > 1) ISSUE(1, 1);

    int cur = 0;
    for (int t = 0; t < T; ++t) {
        if (t + 1 < T) {
            if constexpr (BN == 128)
                asm volatile("s_waitcnt vmcnt(4)" ::: "memory");
            else
                asm volatile("s_waitcnt vmcnt(3)" ::: "memory");
        } else {
            asm volatile("s_waitcnt vmcnt(0)" ::: "memory");
        }
        __builtin_amdgcn_s_barrier();
        if (t + 2 < T) {
            int nb = cur + 2; if (nb >= 3) nb -= 3;
            ISSUE(t + 2, nb);
        }
        bf16x8 af[4], bfr[NJ];
        #pragma unroll
        for (int i = 0; i < 4; ++i) {
            int r = wr * 64 + i * 16 + lr;
            af[i] = *(const bf16x8*)&As[cur][r * 32 + ((G ^ ((r >> 1) & 3)) << 3)];
        }
        #pragma unroll
        for (int j = 0; j < NJ; ++j) {
            int r = wc * WN + j * 16 + lr;
            bfr[j] = *(const bf16x8*)&Bs[cur][r * 32 + ((G ^ ((r >> 1) & 3)) << 3)];
        }
        #pragma unroll
        for (int i = 0; i < 4; ++i)
            #pragma unroll
            for (int j = 0; j < NJ; ++j)
                acc[i][j] = __builtin_amdgcn_mfma_f32_16x16x32_bf16(
                    af[i], bfr[j], acc[i][j], 0, 0, 0);
        __builtin_amdgcn_s_barrier();   // reads done before buffer reuse
        cur = (cur + 1 == 3) ? 0 : cur + 1;
    }
#undef ISSUE

    int rbase = m0 + wr * 64 + (lane >> 4) * 4;
    int cbase = n0 + wc * WN + lr;
    #pragma unroll
    for (int i = 0; i < 4; ++i)
        #pragma unroll
        for (int j = 0; j < NJ; ++j)
            #pragma unroll
            for (int r = 0; r < 4; ++r) {
                int row = rbase + i * 16 + r;
                int col = cbase + j * 16;
                float c = acc[i][j][r];
                if (EPI == 0) {
                    if (col < DINNER)
                        ((unsigned short*)out0)[(size_t)row * DINNER + col] = f2bf(c);
                    else
                        ((unsigned short*)out1)[(size_t)row * DINNER + (col - DINNER)] = f2bf(c);
                } else if (EPI == 2) {
                    out0[(size_t)blockIdx.z * MROWS * N + (size_t)row * N + col] = c;
                } else if (EPI == 3) {
                    if (col < XDIM)
                        out0[(size_t)blockIdx.z * MROWS * XDIM +
                             (size_t)row * XDIM + col] = c;
                } else {
                    float cc = c + bias[col];
                    cc = fmaxf(cc, 0.f) + log1pf(__expf(-fabsf(cc)));
                    ((unsigned short*)out0)[(size_t)row * N + col] = f2bf(cc);
                }
            }
}

// ---------------- xproj reduce: fp32 dbl + bf16 db64 -----------------------
#define XSPLIT 16
__global__ __launch_bounds__(256) void xprojR_k(
    const float* __restrict__ part, float* __restrict__ dbl,
    unsigned short* __restrict__ db64)
{
    int idx = blockIdx.x * 256 + threadIdx.x;   // MROWS*XDIM
    float s = 0.f;
    #pragma unroll
    for (int k = 0; k < XSPLIT; ++k)
        s += part[(size_t)k * MROWS * XDIM + idx];
    dbl[idx] = s;
    int col = idx % XDIM;
    if (col < DTRANK)
        db64[(size_t)(idx / XDIM) * DTRANK + col] = f2bf(s);
}

// ------ Causal conv (K=4) + SiLU, t-blocked: 4 channels x 4 timesteps ------
// R10 WIN (-27us): 7 input rows per 4 outputs (1.75 loads/elem vs 4),
// weights/bias loaded once per 4 outputs. 1024 blocks = 4/CU = 16 waves/CU.
__global__ __launch_bounds__(256) void conv4_k(const unsigned short* __restrict__ u,
    const float* __restrict__ cw, const float* __restrict__ cb,
    unsigned short* __restrict__ out)
{
    int idx = blockIdx.x * 256 + threadIdx.x;    // B*L*E/16
    int c4 = idx & (DINNER / 4 - 1);             // 0..511
    int t4 = (idx >> 9) & (SEQLEN / 4 - 1);      // 0..255
    int b  = idx >> 17;
    int e0 = c4 * 4;
    int t  = t4 * 4;
    size_t base = (size_t)b * SEQLEN * DINNER + (size_t)t * DINNER + e0;
    ushort4 rows[7];                             // t-3 .. t+3
    #pragma unroll
    for (int r = 0; r < 7; ++r) {
        int tt = t + r - 3;
        ushort4 zv = {0, 0, 0, 0};
        rows[r] = (tt >= 0) ?
            *(const ushort4*)(u + base + (size_t)(r - 3) * DINNER) : zv;
    }
    float4 wv[4];
    float bias4[4];
    #pragma unroll
    for (int j = 0; j < 4; ++j) {
        wv[j] = *(const float4*)(cw + (size_t)(e0 + j) * KCONV);
        bias4[j] = cb[e0 + j];
    }
    #pragma unroll
    for (int q = 0; q < 4; ++q) {                // output t+q uses rows q..q+3
        ushort4 o;
        #pragma unroll
        for (int j = 0; j < 4; ++j) {
            float acc = bias4[j];
            acc = fmaf(bf2f(((const unsigned short*)&rows[q + 0])[j]), wv[j].x, acc);
            acc = fmaf(bf2f(((const unsigned short*)&rows[q + 1])[j]), wv[j].y, acc);
            acc = fmaf(bf2f(((const unsigned short*)&rows[q + 2])[j]), wv[j].z, acc);
            acc = fmaf(bf2f(((const unsigned short*)&rows[q + 3])[j]), wv[j].w, acc);
            ((unsigned short*)&o)[j] = f2bf(acc / (1.f + __expf(-acc)));
        }
        *(ushort4*)(out + base + (size_t)q * DINNER) = o;
    }
}

// ---------------- Merged chunked selective scan, S=8 states/thread ---------
// R0 structure — FLOOR. R1 (more waves), R2 ([e][t] layout), R3 (manual
// pipeline), R5 (SUN=8) all regressed. Do not touch.
template<int CTRL>
__device__ __forceinline__ float qadd(float x) {
    int y = __builtin_amdgcn_update_dpp(0, __float_as_int(x), CTRL, 0xF, 0xF, true);
    return x + __int_as_float(y);
}

__global__ __launch_bounds__(512) void scan_k(
    const unsigned short* __restrict__ dt, const unsigned short* __restrict__ uc,
    const float* __restrict__ dbl, const unsigned short* __restrict__ z,
    const float* __restrict__ A_log, const float* __restrict__ Dp,
    unsigned short* __restrict__ yout)
{
    __shared__ float sAlo[NCHUNK][8][2][4], sAhi[NCHUNK][8][2][4];
    __shared__ float sBlo[NCHUNK][8][2][4], sBhi[NCHUNK][8][2][4];
    int tid = threadIdx.x;
    int sub = tid & 1;              // low/high 8 states
    int ei  = (tid >> 1) & 7;       // e within block
    int ch  = tid >> 4;             // chunk
    int bid = blockIdx.x;
    int blk = (bid & 7) * 64 + (bid >> 3);   // 512 blocks, bijective
    int eg  = blk & 255;
    int b   = blk >> 8;
    int e   = eg * 8 + ei;

    const float L2E = 1.4426950408889634f;
    float AstL2[8];
    {
        const float* ap = A_log + (size_t)e * DSTATE + sub * 8;
        #pragma unroll
        for (int q = 0; q < 2; ++q) {
            float4 v = *(const float4*)(ap + q * 4);
            AstL2[q * 4 + 0] = -__expf(v.x) * L2E;
            AstL2[q * 4 + 1] = -__expf(v.y) * L2E;
            AstL2[q * 4 + 2] = -__expf(v.z) * L2E;
            AstL2[q * 4 + 3] = -__expf(v.w) * L2E;
        }
    }
    size_t base_e = (size_t)b * SEQLEN * DINNER + e;
    size_t base_x = (size_t)b * SEQLEN * XDIM + DTRANK + sub * 8;
    int t0c = ch * CLEN;

    // ---- phase A: chunk transfer with h_in = 0
    float h[8] = {0.f, 0.f, 0.f, 0.f, 0.f, 0.f, 0.f, 0.f};
    float ssum = 0.f;
    for (int t0 = t0c; t0 < t0c + CLEN; t0 += SUN) {
        float sdt[SUN], su[SUN];
        #pragma unroll
        for (int u = 0; u < SUN; ++u) {
            size_t te = base_e + (size_t)(t0 + u) * DINNER;
            sdt[u] = bf2f(dt[te]);
            su[u]  = bf2f(uc[te]);
        }
        #pragma unroll
        for (int u = 0; u < SUN; ++u) {
            const float* dx = dbl + base_x + (size_t)(t0 + u) * XDIM;
            float4 bn0 = *(const float4*)(dx);
            float4 bn1 = *(const float4*)(dx + 4);
            float dtu = sdt[u] * su[u];
            ssum += sdt[u];
            h[0] = fmaf(__builtin_amdgcn_exp2f(sdt[u] * AstL2[0]), h[0], dtu * bn0.x);
            h[1] = fmaf(__builtin_amdgcn_exp2f(sdt[u] * AstL2[1]), h[1], dtu * bn0.y);
            h[2] = fmaf(__builtin_amdgcn_exp2f(sdt[u] * AstL2[2]), h[2], dtu * bn0.z);
            h[3] = fmaf(__builtin_amdgcn_exp2f(sdt[u] * AstL2[3]), h[3], dtu * bn0.w);
            h[4] = fmaf(__builtin_amdgcn_exp2f(sdt[u] * AstL2[4]), h[4], dtu * bn1.x);
            h[5] = fmaf(__builtin_amdgcn_exp2f(sdt[u] * AstL2[5]), h[5], dtu * bn1.y);
            h[6] = fmaf(__builtin_amdgcn_exp2f(sdt[u] * AstL2[6]), h[6], dtu * bn1.z);
            h[7] = fmaf(__builtin_amdgcn_exp2f(sdt[u] * AstL2[7]), h[7], dtu * bn1.w);
        }
    }
    float a_[8];
    #pragma unroll
    for (int i = 0; i < 8; ++i) a_[i] = __builtin_amdgcn_exp2f(AstL2[i] * ssum);
    *(f32x4*)&sAlo[ch][ei][sub][0] = *(f32x4*)&a_[0];
    *(f32x4*)&sAhi[ch][ei][sub][0] = *(f32x4*)&a_[4];
    *(f32x4*)&sBlo[ch][ei][sub][0] = *(f32x4*)&h[0];
    *(f32x4*)&sBhi[ch][ei][sub][0] = *(f32x4*)&h[4];
    __syncthreads();

    // ---- Hillis-Steele inclusive scan over ch (composition semigroup)
    #pragma unroll
    for (int s = 1; s < NCHUNK; s <<= 1) {
        float pa[8], pb[8];
        bool act = (ch >= s);
        if (act) {
            *(f32x4*)&pa[0] = *(const f32x4*)&sAlo[ch - s][ei][sub][0];
            *(f32x4*)&pa[4] = *(const f32x4*)&sAhi[ch - s][ei][sub][0];
            *(f32x4*)&pb[0] = *(const f32x4*)&sBlo[ch - s][ei][sub][0];
            *(f32x4*)&pb[4] = *(const f32x4*)&sBhi[ch - s][ei][sub][0];
        }
        __syncthreads();
        if (act) {
            #pragma unroll
            for (int i = 0; i < 8; ++i) {
                h[i]  = fmaf(a_[i], pb[i], h[i]);
                a_[i] *= pa[i];
            }
            *(f32x4*)&sAlo[ch][ei][sub][0] = *(f32x4*)&a_[0];
            *(f32x4*)&sAhi[ch][ei][sub][0] = *(f32x4*)&a_[4];
            *(f32x4*)&sBlo[ch][ei][sub][0] = *(f32x4*)&h[0];
            *(f32x4*)&sBhi[ch][ei][sub][0] = *(f32x4*)&h[4];
        }
        __syncthreads();
    }

    // h0 for chunk ch = inclusive state of chunk ch-1 (0 for ch==0)
    if (ch > 0) {
        *(f32x4*)&h[0] = *(const f32x4*)&sBlo[ch - 1][ei][sub][0];
        *(f32x4*)&h[4] = *(const f32x4*)&sBhi[ch - 1][ei][sub][0];
    } else {
        #pragma unroll
        for (int i = 0; i < 8; ++i) h[i] = 0.f;
    }

    float Dk = Dp[e];
    // ---- phase C: re-run chunk from h0, emit gated y
    for (int t0 = t0c; t0 < t0c + CLEN; t0 += SUN) {
        float sdt[SUN], su[SUN], zz[SUN];
        #pragma unroll
        for (int u = 0; u < SUN; ++u) {
            size_t te = base_e + (size_t)(t0 + u) * DINNER;
            sdt[u] = bf2f(dt[te]);
            su[u]  = bf2f(uc[te]);
            zz[u]  = bf2f(z[te]);
        }
        #pragma unroll
        for (int u = 0; u < SUN; ++u) {
            const float* dx = dbl + base_x + (size_t)(t0 + u) * XDIM;
            float4 bn0 = *(const float4*)(dx);
            float4 bn1 = *(const float4*)(dx + 4);
            float4 cn0 = *(const float4*)(dx + 16);
            float4 cn1 = *(const float4*)(dx + 20);
            float dtu = sdt[u] * su[u];
            h[0] = fmaf(__builtin_amdgcn_exp2f(sdt[u] * AstL2[0]), h[0], dtu * bn0.x);
            h[1] = fmaf(__builtin_amdgcn_exp2f(sdt[u] * AstL2[1]), h[1], dtu * bn0.y);
            h[2] = fmaf(__builtin_amdgcn_exp2f(sdt[u] * AstL2[2]), h[2], dtu * bn0.z);
            h[3] = fmaf(__builtin_amdgcn_exp2f(sdt[u] * AstL2[3]), h[3], dtu * bn0.w);
            h[4] = fmaf(__builtin_amdgcn_exp2f(sdt[u] * AstL2[4]), h[4], dtu * bn1.x);
            h[5] = fmaf(__builtin_amdgcn_exp2f(sdt[u] * AstL2[5]), h[5], dtu * bn1.y);
            h[6] = fmaf(__builtin_amdgcn_exp2f(sdt[u] * AstL2[6]), h[6], dtu * bn1.z);
            h[7] = fmaf(__builtin_amdgcn_exp2f(sdt[u] * AstL2[7]), h[7], dtu * bn1.w);
            float p = h[0] * cn0.x + h[1] * cn0.y + h[2] * cn0.z + h[3] * cn0.w
                    + h[4] * cn1.x + h[5] * cn1.y + h[6] * cn1.z + h[7] * cn1.w;
            p = qadd<0xB1>(p);   // partner-sub sum (lane^1)
            if (sub == 0) {
                float zvv = zz[u];
                float yv = p + su[u] * Dk;
                yout[base_e + (size_t)(t0 + u) * DINNER] =
                    f2bf(yv * (zvv / (1.f + __expf(-zvv))));
            }
        }
    }
}

extern "C" void kernel_launch(void* const* d_in, const int* in_sizes, int n_in,
                              void* d_out, int out_size, void* d_ws, size_t ws_size,
                              hipStream_t stream)
{
    const float* x         = (const float*)d_in[0];
    const float* norm_w    = (const float*)d_in[1];
    const float* norm_b    = (const float*)d_in[2];
    const float* in_proj_w = (const float*)d_in[3];
    const float* conv_w    = (const float*)d_in[4];
    const float* conv_b    = (const float*)d_in[5];
    const float* xproj_w   = (const float*)d_in[6];
    const float* dtproj_w  = (const float*)d_in[7];
    const float* dtproj_b  = (const float*)d_in[8];
    const float* A_log     = (const float*)d_in[9];
    const float* skip_D    = (const float*)d_in[10];
    const float* out_proj_w= (const float*)d_in[11];
    const float* fn_w      = (const float*)d_in[12];
    const float* fn_b      = (const float*)d_in[13];

    float* resid = (float*)d_out;
    float* ws    = (float*)d_ws;
    const size_t M1 = 1024 * 1024;
    unsigned short* wtib = (unsigned short*)(ws);              // 4x[4096][1024]
    unsigned short* wtob = (unsigned short*)(ws + 8  * M1);    // 4x[1024][2048]
    unsigned short* wtxp = (unsigned short*)(ws + 12 * M1);    // 4x[128pad][2048]
    unsigned short* wtdt = (unsigned short*)(ws + 12 * M1 + M1 / 2); // 4x[2048][64]
    unsigned short* hb16 = (unsigned short*)(ws + 13 * M1);    // [2048][1024]
    unsigned short* ub16 = (unsigned short*)(ws + 14 * M1);    // [2048][2048]
    unsigned short* zb16 = (unsigned short*)(ws + 16 * M1);    // [2048][2048]
    unsigned short* ucb16= (unsigned short*)(ws + 18 * M1);    // [2048][2048]
    unsigned short* dtb16= (unsigned short*)(ws + 20 * M1);    // [2048][2048]
    float*          dblb = ws + 22 * M1;                       // [2048][96] fp32
    unsigned short* db64 = (unsigned short*)(ws + 22 * M1 + M1 / 4); // [2048][64]
    unsigned short* yb16 = (unsigned short*)(ws + 23 * M1);    // [2048][2048]
    float*          xpart= ws + 25 * M1;                       // 16x[2048][96]
    float*          pout = ws + 28 * M1;                       // 4x[2048][1024]

    wtr2_k<<<dim3(2 * DINNER / 64, DMODEL / 64, NBLOCKS), 256, 0, stream>>>(
        in_proj_w, wtib, 2 * DINNER, DMODEL,
        (long long)DMODEL * 2 * DINNER, (long long)2 * DINNER * DMODEL);
    wtr2_k<<<dim3(DMODEL / 64, DINNER / 64, NBLOCKS), 256, 0, stream>>>(
        out_proj_w, wtob, DMODEL, DINNER,
        (long long)DINNER * DMODEL, (long long)DMODEL * DINNER);
    wtr2_k<<<dim3(2, DINNER / 64, NBLOCKS), 256, 0, stream>>>(
        xproj_w, wtxp, XDIM, DINNER,
        (long long)DINNER * XDIM, (long long)128 * DINNER);
    wtr2_k<<<dim3(DINNER / 64, 1, NBLOCKS), 256, 0, stream>>>(
        dtproj_w, wtdt, DINNER, DTRANK,
        (long long)DTRANK * DINNER, (long long)DINNER * DTRANK);

    lnc_k<<<MROWS, 256, 0, stream>>>(x, norm_w, norm_b, resid, hb16);

    for (int i = 0; i < NBLOCKS; ++i) {
        // in_proj MFMA (BN=128, 512 blocks, XCD swizzle) -> u bf16 | z bf16
        mgemm6_k<0, 128, 32, 16><<<dim3(2 * DINNER / 128, MROWS / 128, 1), 256, 0, stream>>>(
            hb16, wtib + (size_t)i * 2 * DINNER * DMODEL,
            (float*)ub16, (float*)zb16, nullptr, 2 * DINNER, DMODEL, DMODEL);
        // conv + SiLU, t-blocked 4x4 (1024 blocks)
        conv4_k<<<(MROWS * DINNER / 16) / 256, 256, 0, stream>>>(
            ub16, conv_w + (size_t)i * DINNER * KCONV,
            conv_b + (size_t)i * DINNER, ucb16);
        // xproj split-K MFMA (BN=64, 1024 blocks = 4/CU) -> partials -> reduce
        mgemm6_k<3, 64><<<dim3(2, MROWS / 128, XSPLIT), 256, 0, stream>>>(
            ucb16, wtxp + (size_t)i * 128 * DINNER,
            xpart, nullptr, nullptr, XDIM, DINNER, DINNER / XSPLIT);
        xprojR_k<<<(MROWS * XDIM) / 256, 256, 0, stream>>>(xpart, dblb, db64);
        // dtproj MFMA (BN=64) + bias + softplus -> bf16
        mgemm6_k<4, 64><<<dim3(DINNER / 64, MROWS / 128, 1), 256, 0, stream>>>(
            db64, wtdt + (size_t)i * DINNER * DTRANK,
            (float*)dtb16, nullptr, dtproj_b + (size_t)i * DINNER,
            DINNER, DTRANK, DTRANK);
        // merged chunked scan (S=8, exp2, R0 structure — floor)
        scan_k<<<BATCH * DINNER / 8, 512, 0, stream>>>(
            dtb16, ucb16, dblb, zb16,
            A_log + (size_t)i * DINNER * DSTATE, skip_D + (size_t)i * DINNER, yb16);
        // out_proj split-K x4 (BN=128, XCD swizzle) -> partials
        mgemm6_k<2, 128, 8, 16><<<dim3(DMODEL / 128, MROWS / 128, 4), 256, 0, stream>>>(
            yb16, wtob + (size_t)i * DMODEL * DINNER,
            pout, nullptr, nullptr, DMODEL, DINNER, DINNER / 4);
        // fused reduce + residual + next LN (or final LN)
        if (i < NBLOCKS - 1)
            predln_k<0><<<MROWS, 256, 0, stream>>>(pout, resid,
                norm_w + (i + 1) * DMODEL, norm_b + (i + 1) * DMODEL,
                hb16, nullptr);
        else
            predln_k<1><<<MROWS, 256, 0, stream>>>(pout, resid,
                fn_w, fn_b, nullptr, resid);
    }
}

// Round 12
// 542.816 us; speedup vs baseline: 1.0046x; 1.0046x over previous
//
#include <hip/hip_runtime.h>
#include <hip/hip_bf16.h>
#include <math.h>

#define BATCH 2
#define SEQLEN 1024
#define DMODEL 1024
#define DINNER 2048
#define DSTATE 16
#define DTRANK 64
#define XDIM 96
#define KCONV 4
#define NBLOCKS 4
#define MROWS (BATCH*SEQLEN)   // 2048

#define NCHUNK 32
#define CLEN (SEQLEN/NCHUNK)   // 32
#define SUN 4

typedef short bf16x8 __attribute__((ext_vector_type(8)));
typedef unsigned short u16x8 __attribute__((ext_vector_type(8)));
typedef float f32x4 __attribute__((ext_vector_type(4)));

__device__ __forceinline__ unsigned short f2bf(float x) {
    union { float f; unsigned u; } c; c.f = x;
    unsigned r = c.u + 0x7FFFu + ((c.u >> 16) & 1u);   // RNE
    return (unsigned short)(r >> 16);
}
__device__ __forceinline__ float bf2f(unsigned short h) {
    union { unsigned u; float f; } c; c.u = (unsigned)h << 16;
    return c.f;
}

__device__ __forceinline__ void gload16(const void* src, void* dst) {
    __builtin_amdgcn_global_load_lds(
        (const __attribute__((address_space(1))) void*)src,
        (__attribute__((address_space(3))) void*)dst, 16, 0, 0);
}

// ---------------- LayerNorm + x copy (entry) -------------------------------
__global__ __launch_bounds__(256) void lnc_k(const float* __restrict__ x,
    const float* __restrict__ w, const float* __restrict__ b,
    float* __restrict__ resid, unsigned short* __restrict__ out)
{
    int row = blockIdx.x;
    int tid = threadIdx.x;
    size_t off = (size_t)row * DMODEL + tid * 4;
    float4 v = *(const float4*)(x + off);
    *(float4*)(resid + off) = v;
    float s  = v.x + v.y + v.z + v.w;
    float sq = v.x*v.x + v.y*v.y + v.z*v.z + v.w*v.w;
    #pragma unroll
    for (int o = 32; o > 0; o >>= 1) {
        s  += __shfl_down(s, o);
        sq += __shfl_down(sq, o);
    }
    __shared__ float ss[4], sq4[4];
    int wid = tid >> 6;
    if ((tid & 63) == 0) { ss[wid] = s; sq4[wid] = sq; }
    __syncthreads();
    if (tid == 0) {
        ss[0]  = ss[0] + ss[1] + ss[2] + ss[3];
        sq4[0] = sq4[0] + sq4[1] + sq4[2] + sq4[3];
    }
    __syncthreads();
    float mean = ss[0] * (1.0f / DMODEL);
    float var  = sq4[0] * (1.0f / DMODEL) - mean * mean;
    float rstd = rsqrtf(var + 1e-5f);
    float4 wv = *(const float4*)(w + tid * 4);
    float4 bv = *(const float4*)(b + tid * 4);
    ushort4 h;
    h.x = f2bf((v.x - mean) * rstd * wv.x + bv.x);
    h.y = f2bf((v.y - mean) * rstd * wv.y + bv.y);
    h.z = f2bf((v.z - mean) * rstd * wv.z + bv.z);
    h.w = f2bf((v.w - mean) * rstd * wv.w + bv.w);
    *(ushort4*)(out + off) = h;
}

// ---- fused: split-K reduce + residual add + LayerNorm ---------------------
template<int FINAL>
__global__ __launch_bounds__(256) void predln_k(
    const float* __restrict__ pout, float* __restrict__ resid,
    const float* __restrict__ w, const float* __restrict__ b,
    unsigned short* __restrict__ hb16, float* __restrict__ fout)
{
    int row = blockIdx.x;
    int tid = threadIdx.x;
    const size_t MN = (size_t)MROWS * DMODEL;
    size_t off = (size_t)row * DMODEL + tid * 4;
    float4 p0 = *(const float4*)(pout + off);
    float4 p1 = *(const float4*)(pout + off + MN);
    float4 p2 = *(const float4*)(pout + off + 2 * MN);
    float4 p3 = *(const float4*)(pout + off + 3 * MN);
    float4 r  = *(const float4*)(resid + off);
    float4 v;
    v.x = r.x + (p0.x + p1.x) + (p2.x + p3.x);
    v.y = r.y + (p0.y + p1.y) + (p2.y + p3.y);
    v.z = r.z + (p0.z + p1.z) + (p2.z + p3.z);
    v.w = r.w + (p0.w + p1.w) + (p2.w + p3.w);
    if (!FINAL) *(float4*)(resid + off) = v;

    float s  = v.x + v.y + v.z + v.w;
    float sq = v.x*v.x + v.y*v.y + v.z*v.z + v.w*v.w;
    #pragma unroll
    for (int o = 32; o > 0; o >>= 1) {
        s  += __shfl_down(s, o);
        sq += __shfl_down(sq, o);
    }
    __shared__ float ss[4], sq4[4];
    int wid = tid >> 6;
    if ((tid & 63) == 0) { ss[wid] = s; sq4[wid] = sq; }
    __syncthreads();
    if (tid == 0) {
        ss[0]  = ss[0] + ss[1] + ss[2] + ss[3];
        sq4[0] = sq4[0] + sq4[1] + sq4[2] + sq4[3];
    }
    __syncthreads();
    float mean = ss[0] * (1.0f / DMODEL);
    float var  = sq4[0] * (1.0f / DMODEL) - mean * mean;
    float rstd = rsqrtf(var + 1e-5f);
    float4 wv = *(const float4*)(w + tid * 4);
    float4 bv = *(const float4*)(b + tid * 4);
    float o0 = (v.x - mean) * rstd * wv.x + bv.x;
    float o1 = (v.y - mean) * rstd * wv.y + bv.y;
    float o2 = (v.z - mean) * rstd * wv.z + bv.z;
    float o3 = (v.w - mean) * rstd * wv.w + bv.w;
    if (FINAL) {
        *(float4*)(fout + off) = make_float4(o0, o1, o2, o3);
    } else {
        ushort4 h;
        h.x = f2bf(o0); h.y = f2bf(o1); h.z = f2bf(o2); h.w = f2bf(o3);
        *(ushort4*)(hb16 + off) = h;
    }
}

// ------ guarded weight transpose+convert: W[K][N] fp32 -> WT[N][K] bf16 ----
__global__ __launch_bounds__(256) void wtr2_k(
    const float* __restrict__ W, unsigned short* __restrict__ WT,
    int N, int K, long long wstride, long long wtstride)
{
    const float* Wl = W + (size_t)blockIdx.z * wstride;
    unsigned short* WTl = WT + (size_t)blockIdx.z * wtstride;
    __shared__ float T[64][65];
    int n0 = blockIdx.x * 64, k0 = blockIdx.y * 64;
    int tid = threadIdx.x;
    int kk = tid >> 4, nn = (tid & 15) * 4;
    #pragma unroll
    for (int p = 0; p < 4; ++p) {
        float4 v = make_float4(0.f, 0.f, 0.f, 0.f);
        if (n0 + nn + 4 <= N)
            v = *(const float4*)(Wl + (size_t)(k0 + p * 16 + kk) * N + n0 + nn);
        T[p * 16 + kk][nn + 0] = v.x;
        T[p * 16 + kk][nn + 1] = v.y;
        T[p * 16 + kk][nn + 2] = v.z;
        T[p * 16 + kk][nn + 3] = v.w;
    }
    __syncthreads();
    int n2 = tid >> 4, k2 = (tid & 15) * 4;
    #pragma unroll
    for (int p = 0; p < 4; ++p) {
        int nrow = n0 + p * 16 + n2;
        ushort4 h = {0, 0, 0, 0};
        if (nrow < N) {
            h.x = f2bf(T[k2 + 0][p * 16 + n2]);
            h.y = f2bf(T[k2 + 1][p * 16 + n2]);
            h.z = f2bf(T[k2 + 2][p * 16 + n2]);
            h.w = f2bf(T[k2 + 3][p * 16 + n2]);
        }
        *(ushort4*)(WTl + (size_t)nrow * K + k0 + k2) = h;
    }
}

// ---------------- bf16 MFMA GEMM v6: 3-buffer counted-vmcnt pipeline -------
// Final config (R10 best): 16x16x32, BN=128 for in_proj/out_proj/xproj,
// BN=64 for dtproj. Tested-and-rejected levers: XCD swizzle (R6, kept,
// neutral), 4-buf one-barrier (R7, 0), 256x128 tile (R8, -23us), 32x32x16
// MFMA (R9, -5us), xproj BN=64 4-blk/CU (R11, -2us). Staging-volume-bound
// at these short-K shapes — this schedule family's measured ceiling.
template<int EPI, int BN, int SWZX = 0, int SWZY = 0>
__global__ __launch_bounds__(256) void mgemm6_k(
    const unsigned short* __restrict__ A,
    const unsigned short* __restrict__ BT,
    float* __restrict__ out0, float* __restrict__ out1,
    const float* __restrict__ bias,
    int N, int Kf, int Kloc)
{
    constexpr int WN = BN / 2;
    constexpr int NJ = WN / 16;
    __shared__ unsigned short As[3][128 * 32];
    __shared__ unsigned short Bs[3][BN * 32];
    int tid = threadIdx.x;
    int lane = tid & 63, w = tid >> 6;
    int wr = w >> 1, wc = w & 1;
    int bxx = blockIdx.x, byy = blockIdx.y;
    if constexpr (SWZX > 0) {
        constexpr int TOT = SWZX * SWZY;
        int f = bxx + SWZX * byy;
        int nf = (f & 7) * (TOT / 8) + (f >> 3);
        bxx = nf % SWZX; byy = nf / SWZX;
    }
    int m0 = byy * 128, n0 = bxx * BN;
    int lr = lane & 15, G = lane >> 4;

    int ra0 = w * 32 + (lane >> 2);
    int ra1 = ra0 + 16;
    int ga0 = (lane & 3) ^ ((ra0 >> 1) & 3);
    int ga1 = (lane & 3) ^ ((ra1 >> 1) & 3);
    int rb0 = w * (BN / 4) + (lane >> 2);
    int gb0 = (lane & 3) ^ ((rb0 >> 1) & 3);
    int rb1 = rb0 + 16;
    int gb1 = (lane & 3) ^ ((rb1 >> 1) & 3);

    int kz = blockIdx.z * Kloc;
    const unsigned short* pa0 = A  + (size_t)(m0 + ra0) * Kf + kz + ga0 * 8;
    const unsigned short* pa1 = A  + (size_t)(m0 + ra1) * Kf + kz + ga1 * 8;
    const unsigned short* pb0 = BT + (size_t)(n0 + rb0) * Kf + kz + gb0 * 8;
    const unsigned short* pb1 = BT + (size_t)(n0 + rb1) * Kf + kz + gb1 * 8;
    int dA0 = (w * 32) * 32, dA1 = dA0 + 16 * 32;
    int dB0 = (w * (BN / 4)) * 32, dB1 = dB0 + 16 * 32;

#define ISSUE(tt, bufi) do {                                   \
        gload16(pa0 + (tt) * 32, &As[bufi][dA0]);              \
        gload16(pa1 + (tt) * 32, &As[bufi][dA1]);              \
        gload16(pb0 + (tt) * 32, &Bs[bufi][dB0]);              \
        if (BN == 128) gload16(pb1 + (tt) * 32, &Bs[bufi][dB1]); \
    } while (0)

    f32x4 acc[4][NJ] = {};
    int T = Kloc / 32;

    ISSUE(0, 0);
    if (T > 1) ISSUE(1, 1);

    int cur = 0;
    for (int t = 0; t < T; ++t) {
        if (t + 1 < T) {
            if constexpr (BN == 128)
                asm volatile("s_waitcnt vmcnt(4)" ::: "memory");
            else
                asm volatile("s_waitcnt vmcnt(3)" ::: "memory");
        } else {
            asm volatile("s_waitcnt vmcnt(0)" ::: "memory");
        }
        __builtin_amdgcn_s_barrier();
        if (t + 2 < T) {
            int nb = cur + 2; if (nb >= 3) nb -= 3;
            ISSUE(t + 2, nb);
        }
        bf16x8 af[4], bfr[NJ];
        #pragma unroll
        for (int i = 0; i < 4; ++i) {
            int r = wr * 64 + i * 16 + lr;
            af[i] = *(const bf16x8*)&As[cur][r * 32 + ((G ^ ((r >> 1) & 3)) << 3)];
        }
        #pragma unroll
        for (int j = 0; j < NJ; ++j) {
            int r = wc * WN + j * 16 + lr;
            bfr[j] = *(const bf16x8*)&Bs[cur][r * 32 + ((G ^ ((r >> 1) & 3)) << 3)];
        }
        #pragma unroll
        for (int i = 0; i < 4; ++i)
            #pragma unroll
            for (int j = 0; j < NJ; ++j)
                acc[i][j] = __builtin_amdgcn_mfma_f32_16x16x32_bf16(
                    af[i], bfr[j], acc[i][j], 0, 0, 0);
        __builtin_amdgcn_s_barrier();   // reads done before buffer reuse
        cur = (cur + 1 == 3) ? 0 : cur + 1;
    }
#undef ISSUE

    int rbase = m0 + wr * 64 + (lane >> 4) * 4;
    int cbase = n0 + wc * WN + lr;
    #pragma unroll
    for (int i = 0; i < 4; ++i)
        #pragma unroll
        for (int j = 0; j < NJ; ++j)
            #pragma unroll
            for (int r = 0; r < 4; ++r) {
                int row = rbase + i * 16 + r;
                int col = cbase + j * 16;
                float c = acc[i][j][r];
                if (EPI == 0) {
                    if (col < DINNER)
                        ((unsigned short*)out0)[(size_t)row * DINNER + col] = f2bf(c);
                    else
                        ((unsigned short*)out1)[(size_t)row * DINNER + (col - DINNER)] = f2bf(c);
                } else if (EPI == 2) {
                    out0[(size_t)blockIdx.z * MROWS * N + (size_t)row * N + col] = c;
                } else if (EPI == 3) {
                    if (col < XDIM)
                        out0[(size_t)blockIdx.z * MROWS * XDIM +
                             (size_t)row * XDIM + col] = c;
                } else {
                    float cc = c + bias[col];
                    cc = fmaxf(cc, 0.f) + log1pf(__expf(-fabsf(cc)));
                    ((unsigned short*)out0)[(size_t)row * N + col] = f2bf(cc);
                }
            }
}

// ---------------- xproj reduce: fp32 dbl + bf16 db64 -----------------------
#define XSPLIT 16
__global__ __launch_bounds__(256) void xprojR_k(
    const float* __restrict__ part, float* __restrict__ dbl,
    unsigned short* __restrict__ db64)
{
    int idx = blockIdx.x * 256 + threadIdx.x;   // MROWS*XDIM
    float s = 0.f;
    #pragma unroll
    for (int k = 0; k < XSPLIT; ++k)
        s += part[(size_t)k * MROWS * XDIM + idx];
    dbl[idx] = s;
    int col = idx % XDIM;
    if (col < DTRANK)
        db64[(size_t)(idx / XDIM) * DTRANK + col] = f2bf(s);
}

// ------ Causal conv (K=4) + SiLU, t-blocked: 4 channels x 4 timesteps ------
// R10 WIN (-27us): 7 input rows per 4 outputs (1.75 loads/elem vs 4),
// weights/bias loaded once per 4 outputs. 1024 blocks = 4/CU = 16 waves/CU.
__global__ __launch_bounds__(256) void conv4_k(const unsigned short* __restrict__ u,
    const float* __restrict__ cw, const float* __restrict__ cb,
    unsigned short* __restrict__ out)
{
    int idx = blockIdx.x * 256 + threadIdx.x;    // B*L*E/16
    int c4 = idx & (DINNER / 4 - 1);             // 0..511
    int t4 = (idx >> 9) & (SEQLEN / 4 - 1);      // 0..255
    int b  = idx >> 17;
    int e0 = c4 * 4;
    int t  = t4 * 4;
    size_t base = (size_t)b * SEQLEN * DINNER + (size_t)t * DINNER + e0;
    ushort4 rows[7];                             // t-3 .. t+3
    #pragma unroll
    for (int r = 0; r < 7; ++r) {
        int tt = t + r - 3;
        ushort4 zv = {0, 0, 0, 0};
        rows[r] = (tt >= 0) ?
            *(const ushort4*)(u + base + (size_t)(r - 3) * DINNER) : zv;
    }
    float4 wv[4];
    float bias4[4];
    #pragma unroll
    for (int j = 0; j < 4; ++j) {
        wv[j] = *(const float4*)(cw + (size_t)(e0 + j) * KCONV);
        bias4[j] = cb[e0 + j];
    }
    #pragma unroll
    for (int q = 0; q < 4; ++q) {                // output t+q uses rows q..q+3
        ushort4 o;
        #pragma unroll
        for (int j = 0; j < 4; ++j) {
            float acc = bias4[j];
            acc = fmaf(bf2f(((const unsigned short*)&rows[q + 0])[j]), wv[j].x, acc);
            acc = fmaf(bf2f(((const unsigned short*)&rows[q + 1])[j]), wv[j].y, acc);
            acc = fmaf(bf2f(((const unsigned short*)&rows[q + 2])[j]), wv[j].z, acc);
            acc = fmaf(bf2f(((const unsigned short*)&rows[q + 3])[j]), wv[j].w, acc);
            ((unsigned short*)&o)[j] = f2bf(acc / (1.f + __expf(-acc)));
        }
        *(ushort4*)(out + base + (size_t)q * DINNER) = o;
    }
}

// ---------------- Merged chunked selective scan, S=8 states/thread ---------
// R0 structure — FLOOR. R1 (more waves), R2 ([e][t] layout), R3 (manual
// pipeline), R5 (SUN=8) all regressed. Do not touch.
template<int CTRL>
__device__ __forceinline__ float qadd(float x) {
    int y = __builtin_amdgcn_update_dpp(0, __float_as_int(x), CTRL, 0xF, 0xF, true);
    return x + __int_as_float(y);
}

__global__ __launch_bounds__(512) void scan_k(
    const unsigned short* __restrict__ dt, const unsigned short* __restrict__ uc,
    const float* __restrict__ dbl, const unsigned short* __restrict__ z,
    const float* __restrict__ A_log, const float* __restrict__ Dp,
    unsigned short* __restrict__ yout)
{
    __shared__ float sAlo[NCHUNK][8][2][4], sAhi[NCHUNK][8][2][4];
    __shared__ float sBlo[NCHUNK][8][2][4], sBhi[NCHUNK][8][2][4];
    int tid = threadIdx.x;
    int sub = tid & 1;              // low/high 8 states
    int ei  = (tid >> 1) & 7;       // e within block
    int ch  = tid >> 4;             // chunk
    int bid = blockIdx.x;
    int blk = (bid & 7) * 64 + (bid >> 3);   // 512 blocks, bijective
    int eg  = blk & 255;
    int b   = blk >> 8;
    int e   = eg * 8 + ei;

    const float L2E = 1.4426950408889634f;
    float AstL2[8];
    {
        const float* ap = A_log + (size_t)e * DSTATE + sub * 8;
        #pragma unroll
        for (int q = 0; q < 2; ++q) {
            float4 v = *(const float4*)(ap + q * 4);
            AstL2[q * 4 + 0] = -__expf(v.x) * L2E;
            AstL2[q * 4 + 1] = -__expf(v.y) * L2E;
            AstL2[q * 4 + 2] = -__expf(v.z) * L2E;
            AstL2[q * 4 + 3] = -__expf(v.w) * L2E;
        }
    }
    size_t base_e = (size_t)b * SEQLEN * DINNER + e;
    size_t base_x = (size_t)b * SEQLEN * XDIM + DTRANK + sub * 8;
    int t0c = ch * CLEN;

    // ---- phase A: chunk transfer with h_in = 0
    float h[8] = {0.f, 0.f, 0.f, 0.f, 0.f, 0.f, 0.f, 0.f};
    float ssum = 0.f;
    for (int t0 = t0c; t0 < t0c + CLEN; t0 += SUN) {
        float sdt[SUN], su[SUN];
        #pragma unroll
        for (int u = 0; u < SUN; ++u) {
            size_t te = base_e + (size_t)(t0 + u) * DINNER;
            sdt[u] = bf2f(dt[te]);
            su[u]  = bf2f(uc[te]);
        }
        #pragma unroll
        for (int u = 0; u < SUN; ++u) {
            const float* dx = dbl + base_x + (size_t)(t0 + u) * XDIM;
            float4 bn0 = *(const float4*)(dx);
            float4 bn1 = *(const float4*)(dx + 4);
            float dtu = sdt[u] * su[u];
            ssum += sdt[u];
            h[0] = fmaf(__builtin_amdgcn_exp2f(sdt[u] * AstL2[0]), h[0], dtu * bn0.x);
            h[1] = fmaf(__builtin_amdgcn_exp2f(sdt[u] * AstL2[1]), h[1], dtu * bn0.y);
            h[2] = fmaf(__builtin_amdgcn_exp2f(sdt[u] * AstL2[2]), h[2], dtu * bn0.z);
            h[3] = fmaf(__builtin_amdgcn_exp2f(sdt[u] * AstL2[3]), h[3], dtu * bn0.w);
            h[4] = fmaf(__builtin_amdgcn_exp2f(sdt[u] * AstL2[4]), h[4], dtu * bn1.x);
            h[5] = fmaf(__builtin_amdgcn_exp2f(sdt[u] * AstL2[5]), h[5], dtu * bn1.y);
            h[6] = fmaf(__builtin_amdgcn_exp2f(sdt[u] * AstL2[6]), h[6], dtu * bn1.z);
            h[7] = fmaf(__builtin_amdgcn_exp2f(sdt[u] * AstL2[7]), h[7], dtu * bn1.w);
        }
    }
    float a_[8];
    #pragma unroll
    for (int i = 0; i < 8; ++i) a_[i] = __builtin_amdgcn_exp2f(AstL2[i] * ssum);
    *(f32x4*)&sAlo[ch][ei][sub][0] = *(f32x4*)&a_[0];
    *(f32x4*)&sAhi[ch][ei][sub][0] = *(f32x4*)&a_[4];
    *(f32x4*)&sBlo[ch][ei][sub][0] = *(f32x4*)&h[0];
    *(f32x4*)&sBhi[ch][ei][sub][0] = *(f32x4*)&h[4];
    __syncthreads();

    // ---- Hillis-Steele inclusive scan over ch (composition semigroup)
    #pragma unroll
    for (int s = 1; s < NCHUNK; s <<= 1) {
        float pa[8], pb[8];
        bool act = (ch >= s);
        if (act) {
            *(f32x4*)&pa[0] = *(const f32x4*)&sAlo[ch - s][ei][sub][0];
            *(f32x4*)&pa[4] = *(const f32x4*)&sAhi[ch - s][ei][sub][0];
            *(f32x4*)&pb[0] = *(const f32x4*)&sBlo[ch - s][ei][sub][0];
            *(f32x4*)&pb[4] = *(const f32x4*)&sBhi[ch - s][ei][sub][0];
        }
        __syncthreads();
        if (act) {
            #pragma unroll
            for (int i = 0; i < 8; ++i) {
                h[i]  = fmaf(a_[i], pb[i], h[i]);
                a_[i] *= pa[i];
            }
            *(f32x4*)&sAlo[ch][ei][sub][0] = *(f32x4*)&a_[0];
            *(f32x4*)&sAhi[ch][ei][sub][0] = *(f32x4*)&a_[4];
            *(f32x4*)&sBlo[ch][ei][sub][0] = *(f32x4*)&h[0];
            *(f32x4*)&sBhi[ch][ei][sub][0] = *(f32x4*)&h[4];
        }
        __syncthreads();
    }

    // h0 for chunk ch = inclusive state of chunk ch-1 (0 for ch==0)
    if (ch > 0) {
        *(f32x4*)&h[0] = *(const f32x4*)&sBlo[ch - 1][ei][sub][0];
        *(f32x4*)&h[4] = *(const f32x4*)&sBhi[ch - 1][ei][sub][0];
    } else {
        #pragma unroll
        for (int i = 0; i < 8; ++i) h[i] = 0.f;
    }

    float Dk = Dp[e];
    // ---- phase C: re-run chunk from h0, emit gated y
    for (int t0 = t0c; t0 < t0c + CLEN; t0 += SUN) {
        float sdt[SUN], su[SUN], zz[SUN];
        #pragma unroll
        for (int u = 0; u < SUN; ++u) {
            size_t te = base_e + (size_t)(t0 + u) * DINNER;
            sdt[u] = bf2f(dt[te]);
            su[u]  = bf2f(uc[te]);
            zz[u]  = bf2f(z[te]);
        }
        #pragma unroll
        for (int u = 0; u < SUN; ++u) {
            const float* dx = dbl + base_x + (size_t)(t0 + u) * XDIM;
            float4 bn0 = *(const float4*)(dx);
            float4 bn1 = *(const float4*)(dx + 4);
            float4 cn0 = *(const float4*)(dx + 16);
            float4 cn1 = *(const float4*)(dx + 20);
            float dtu = sdt[u] * su[u];
            h[0] = fmaf(__builtin_amdgcn_exp2f(sdt[u] * AstL2[0]), h[0], dtu * bn0.x);
            h[1] = fmaf(__builtin_amdgcn_exp2f(sdt[u] * AstL2[1]), h[1], dtu * bn0.y);
            h[2] = fmaf(__builtin_amdgcn_exp2f(sdt[u] * AstL2[2]), h[2], dtu * bn0.z);
            h[3] = fmaf(__builtin_amdgcn_exp2f(sdt[u] * AstL2[3]), h[3], dtu * bn0.w);
            h[4] = fmaf(__builtin_amdgcn_exp2f(sdt[u] * AstL2[4]), h[4], dtu * bn1.x);
            h[5] = fmaf(__builtin_amdgcn_exp2f(sdt[u] * AstL2[5]), h[5], dtu * bn1.y);
            h[6] = fmaf(__builtin_amdgcn_exp2f(sdt[u] * AstL2[6]), h[6], dtu * bn1.z);
            h[7] = fmaf(__builtin_amdgcn_exp2f(sdt[u] * AstL2[7]), h[7], dtu * bn1.w);
            float p = h[0] * cn0.x + h[1] * cn0.y + h[2] * cn0.z + h[3] * cn0.w
                    + h[4] * cn1.x + h[5] * cn1.y + h[6] * cn1.z + h[7] * cn1.w;
            p = qadd<0xB1>(p);   // partner-sub sum (lane^1)
            if (sub == 0) {
                float zvv = zz[u];
                float yv = p + su[u] * Dk;
                yout[base_e + (size_t)(t0 + u) * DINNER] =
                    f2bf(yv * (zvv / (1.f + __expf(-zvv))));
            }
        }
    }
}

extern "C" void kernel_launch(void* const* d_in, const int* in_sizes, int n_in,
                              void* d_out, int out_size, void* d_ws, size_t ws_size,
                              hipStream_t stream)
{
    const float* x         = (const float*)d_in[0];
    const float* norm_w    = (const float*)d_in[1];
    const float* norm_b    = (const float*)d_in[2];
    const float* in_proj_w = (const float*)d_in[3];
    const float* conv_w    = (const float*)d_in[4];
    const float* conv_b    = (const float*)d_in[5];
    const float* xproj_w   = (const float*)d_in[6];
    const float* dtproj_w  = (const float*)d_in[7];
    const float* dtproj_b  = (const float*)d_in[8];
    const float* A_log     = (const float*)d_in[9];
    const float* skip_D    = (const float*)d_in[10];
    const float* out_proj_w= (const float*)d_in[11];
    const float* fn_w      = (const float*)d_in[12];
    const float* fn_b      = (const float*)d_in[13];

    float* resid = (float*)d_out;
    float* ws    = (float*)d_ws;
    const size_t M1 = 1024 * 1024;
    unsigned short* wtib = (unsigned short*)(ws);              // 4x[4096][1024]
    unsigned short* wtob = (unsigned short*)(ws + 8  * M1);    // 4x[1024][2048]
    unsigned short* wtxp = (unsigned short*)(ws + 12 * M1);    // 4x[128pad][2048]
    unsigned short* wtdt = (unsigned short*)(ws + 12 * M1 + M1 / 2); // 4x[2048][64]
    unsigned short* hb16 = (unsigned short*)(ws + 13 * M1);    // [2048][1024]
    unsigned short* ub16 = (unsigned short*)(ws + 14 * M1);    // [2048][2048]
    unsigned short* zb16 = (unsigned short*)(ws + 16 * M1);    // [2048][2048]
    unsigned short* ucb16= (unsigned short*)(ws + 18 * M1);    // [2048][2048]
    unsigned short* dtb16= (unsigned short*)(ws + 20 * M1);    // [2048][2048]
    float*          dblb = ws + 22 * M1;                       // [2048][96] fp32
    unsigned short* db64 = (unsigned short*)(ws + 22 * M1 + M1 / 4); // [2048][64]
    unsigned short* yb16 = (unsigned short*)(ws + 23 * M1);    // [2048][2048]
    float*          xpart= ws + 25 * M1;                       // 16x[2048][96]
    float*          pout = ws + 28 * M1;                       // 4x[2048][1024]

    wtr2_k<<<dim3(2 * DINNER / 64, DMODEL / 64, NBLOCKS), 256, 0, stream>>>(
        in_proj_w, wtib, 2 * DINNER, DMODEL,
        (long long)DMODEL * 2 * DINNER, (long long)2 * DINNER * DMODEL);
    wtr2_k<<<dim3(DMODEL / 64, DINNER / 64, NBLOCKS), 256, 0, stream>>>(
        out_proj_w, wtob, DMODEL, DINNER,
        (long long)DINNER * DMODEL, (long long)DMODEL * DINNER);
    wtr2_k<<<dim3(2, DINNER / 64, NBLOCKS), 256, 0, stream>>>(
        xproj_w, wtxp, XDIM, DINNER,
        (long long)DINNER * XDIM, (long long)128 * DINNER);
    wtr2_k<<<dim3(DINNER / 64, 1, NBLOCKS), 256, 0, stream>>>(
        dtproj_w, wtdt, DINNER, DTRANK,
        (long long)DTRANK * DINNER, (long long)DINNER * DTRANK);

    lnc_k<<<MROWS, 256, 0, stream>>>(x, norm_w, norm_b, resid, hb16);

    for (int i = 0; i < NBLOCKS; ++i) {
        // in_proj MFMA (BN=128, 512 blocks, XCD swizzle) -> u bf16 | z bf16
        mgemm6_k<0, 128, 32, 16><<<dim3(2 * DINNER / 128, MROWS / 128, 1), 256, 0, stream>>>(
            hb16, wtib + (size_t)i * 2 * DINNER * DMODEL,
            (float*)ub16, (float*)zb16, nullptr, 2 * DINNER, DMODEL, DMODEL);
        // conv + SiLU, t-blocked 4x4 (1024 blocks)
        conv4_k<<<(MROWS * DINNER / 16) / 256, 256, 0, stream>>>(
            ub16, conv_w + (size_t)i * DINNER * KCONV,
            conv_b + (size_t)i * DINNER, ucb16);
        // xproj split-K MFMA (BN=128) -> partials -> reduce
        mgemm6_k<3, 128><<<dim3(1, MROWS / 128, XSPLIT), 256, 0, stream>>>(
            ucb16, wtxp + (size_t)i * 128 * DINNER,
            xpart, nullptr, nullptr, XDIM, DINNER, DINNER / XSPLIT);
        xprojR_k<<<(MROWS * XDIM) / 256, 256, 0, stream>>>(xpart, dblb, db64);
        // dtproj MFMA (BN=64) + bias + softplus -> bf16
        mgemm6_k<4, 64><<<dim3(DINNER / 64, MROWS / 128, 1), 256, 0, stream>>>(
            db64, wtdt + (size_t)i * DINNER * DTRANK,
            (float*)dtb16, nullptr, dtproj_b + (size_t)i * DINNER,
            DINNER, DTRANK, DTRANK);
        // merged chunked scan (S=8, exp2, R0 structure — floor)
        scan_k<<<BATCH * DINNER / 8, 512, 0, stream>>>(
            dtb16, ucb16, dblb, zb16,
            A_log + (size_t)i * DINNER * DSTATE, skip_D + (size_t)i * DINNER, yb16);
        // out_proj split-K x4 (BN=128, XCD swizzle) -> partials
        mgemm6_k<2, 128, 8, 16><<<dim3(DMODEL / 128, MROWS / 128, 4), 256, 0, stream>>>(
            yb16, wtob + (size_t)i * DMODEL * DINNER,
            pout, nullptr, nullptr, DMODEL, DINNER, DINNER / 4);
        // fused reduce + residual + next LN (or final LN)
        if (i < NBLOCKS - 1)
            predln_k<0><<<MROWS, 256, 0, stream>>>(pout, resid,
                norm_w + (i + 1) * DMODEL, norm_b + (i + 1) * DMODEL,
                hb16, nullptr);
        else
            predln_k<1><<<MROWS, 256, 0, stream>>>(pout, resid,
                fn_w, fn_b, nullptr, resid);
    }
}